// Round 1
// baseline (332.369 us; speedup 1.0000x reference)
//
#include <hip/hip_runtime.h>

#define Tdim 4096
#define Bdim 8
#define Cdim 64
#define Ldim 15
#define Idim 2048   // T / STRIDE
#define OUTW 4160   // C + C*C
#define G    4      // windows per block
#define RX   (2*G + 27)   // 35 staged x rows
#define RXC  (2*G + 13)   // 21 centered rows

typedef float v4f __attribute__((ext_vector_type(4)));

// One block = G=4 consecutive windows of one batch. 256 threads.
//  P1: stage x[s0-14 .. s0+2(G-1)+14] (35x64) into LDS, zero-padded.
//  P2: compute 21 unique xc rows ONCE; keep mu at the G output positions.
//  P3: WINDOW-OUTER. Per window g: accumulate its 15 taps into a 4x4 tile
//      (16 VGPRs, reused across windows -> low register pressure, 6 blk/CU),
//      reduce sum-of-squares (one barrier, per-g red slot), scale, and store
//      IMMEDIATELY with nontemporal hints. Stores are spread across the
//      compute phase instead of one terminal burst behind two barriers.
__global__ __launch_bounds__(256, 6) void cbp_kernel(const float* __restrict__ x,
                                                     const float* __restrict__ w1,
                                                     const float* __restrict__ w2,
                                                     float* __restrict__ out) {
    __shared__ float xbuf[RX][64];
    __shared__ float xcs[RXC][64];
    __shared__ float mus[G][64];
    __shared__ float red[G][4];

    const int tid = threadIdx.x;
    const int blk = blockIdx.x;
    const int b  = blk >> 9;            // / (Idim/G = 512)
    const int i0 = (blk & 511) << 2;    // first window index
    const int s0 = i0 << 1;             // STRIDE = 2

    // ---- P1: stage 35 rows, float4, zero-padded ----
    const float* xb = x + (size_t)b * (Tdim * Cdim);
    for (int v = tid; v < RX * 16; v += 256) {
        const int r  = v >> 4;
        const int c4 = (v & 15) << 2;
        const int t  = s0 - 14 + r;
        float4 val = make_float4(0.f, 0.f, 0.f, 0.f);
        if (t >= 0 && t < Tdim) val = *(const float4*)(xb + (size_t)t * Cdim + c4);
        *(float4*)(&xbuf[r][c4]) = val;
    }
    __syncthreads();

    // ---- P2: 21 unique xc rows (336 float4 tasks); mu kept at j=7,9,11,13 ----
    for (int v = tid; v < RXC * 16; v += 256) {
        const int j  = v >> 4;
        const int c4 = (v & 15) << 2;
        const int t  = s0 - 7 + j;
        float4 m = make_float4(0.f, 0.f, 0.f, 0.f);
#pragma unroll
        for (int k = 0; k < Ldim; ++k) {
            const float w = w1[k];               // uniform -> s_load, hoisted
            const float4 xv = *(const float4*)(&xbuf[j + k][c4]);
            m.x = fmaf(w, xv.x, m.x);
            m.y = fmaf(w, xv.y, m.y);
            m.z = fmaf(w, xv.z, m.z);
            m.w = fmaf(w, xv.w, m.w);
        }
        const float4 xv = *(const float4*)(&xbuf[j + 7][c4]);
        float4 xc = make_float4(0.f, 0.f, 0.f, 0.f);
        if (t >= 0 && t < Tdim)
            xc = make_float4(xv.x - m.x, xv.y - m.y, xv.z - m.z, xv.w - m.w);
        *(float4*)(&xcs[j][c4]) = xc;
        if (j >= 7 && j <= 13 && ((j - 7) & 1) == 0)
            *(float4*)(&mus[(j - 7) >> 1][c4]) = m;   // always in-range (s0+2g < T)
    }
    __syncthreads();

    // ---- P3: window-outer Gram + immediate scaled store ----
    const int c0 = (tid >> 4) << 2;   // 0..60
    const int d0 = (tid & 15) << 2;   // 0..60

#pragma unroll
    for (int g = 0; g < G; ++g) {
        float acc[4][4];
#pragma unroll
        for (int cc = 0; cc < 4; ++cc)
#pragma unroll
            for (int dd = 0; dd < 4; ++dd) acc[cc][dd] = 0.f;

#pragma unroll
        for (int l = 0; l < Ldim; ++l) {
            const int r = 2 * g + l;                       // static after unroll
            const float4 xd = *(const float4*)(&xcs[r][d0]);   // ds_read_b128
            const float4 xc = *(const float4*)(&xcs[r][c0]);   // ds_read_b128 (bcast)
            const float w  = w2[l];                        // s_load, hoisted
            const float a0 = w * xc.x, a1 = w * xc.y, a2 = w * xc.z, a3 = w * xc.w;
            acc[0][0] = fmaf(a0, xd.x, acc[0][0]);
            acc[0][1] = fmaf(a0, xd.y, acc[0][1]);
            acc[0][2] = fmaf(a0, xd.z, acc[0][2]);
            acc[0][3] = fmaf(a0, xd.w, acc[0][3]);
            acc[1][0] = fmaf(a1, xd.x, acc[1][0]);
            acc[1][1] = fmaf(a1, xd.y, acc[1][1]);
            acc[1][2] = fmaf(a1, xd.z, acc[1][2]);
            acc[1][3] = fmaf(a1, xd.w, acc[1][3]);
            acc[2][0] = fmaf(a2, xd.x, acc[2][0]);
            acc[2][1] = fmaf(a2, xd.y, acc[2][1]);
            acc[2][2] = fmaf(a2, xd.z, acc[2][2]);
            acc[2][3] = fmaf(a2, xd.w, acc[2][3]);
            acc[3][0] = fmaf(a3, xd.x, acc[3][0]);
            acc[3][1] = fmaf(a3, xd.y, acc[3][1]);
            acc[3][2] = fmaf(a3, xd.z, acc[3][2]);
            acc[3][3] = fmaf(a3, xd.w, acc[3][3]);
        }

        // per-window sum of squares
        float ss = 0.f;
#pragma unroll
        for (int cc = 0; cc < 4; ++cc)
#pragma unroll
            for (int dd = 0; dd < 4; ++dd) ss = fmaf(acc[cc][dd], acc[cc][dd], ss);
        if (tid < Cdim) {
            const float m = mus[g][tid];
            ss = fmaf(m, m, ss);
        }
#pragma unroll
        for (int off = 32; off; off >>= 1) ss += __shfl_down(ss, off, 64);
        if ((tid & 63) == 0) red[g][tid >> 6] = ss;
        __syncthreads();   // red[g] complete; per-g slot -> no WAR hazard with g+1

        const float sstot = red[g][0] + red[g][1] + red[g][2] + red[g][3];
        const float sc = rsqrtf(fmaxf(sstot, 1e-12f));

        // immediate scaled store for this window (nontemporal: out > L3)
        float* orow = out + (size_t)(b * Idim + i0 + g) * OUTW;
        if (tid < 16) {
            const float4 m4 = *(const float4*)(&mus[g][tid << 2]);
            v4f mv = { m4.x * sc, m4.y * sc, m4.z * sc, m4.w * sc };
            __builtin_nontemporal_store(mv, (v4f*)(orow + (tid << 2)));
        }
        float* osig = orow + Cdim;
#pragma unroll
        for (int cc = 0; cc < 4; ++cc) {
            v4f v = { acc[cc][0] * sc, acc[cc][1] * sc,
                      acc[cc][2] * sc, acc[cc][3] * sc };
            __builtin_nontemporal_store(v, (v4f*)(osig + (c0 + cc) * Cdim + d0));
        }
    }
}

extern "C" void kernel_launch(void* const* d_in, const int* in_sizes, int n_in,
                              void* d_out, int out_size, void* d_ws, size_t ws_size,
                              hipStream_t stream) {
    const float* x  = (const float*)d_in[0];
    const float* w1 = (const float*)d_in[1];
    const float* w2 = (const float*)d_in[2];
    float* out = (float*)d_out;
    cbp_kernel<<<dim3(Bdim * (Idim / G)), dim3(256), 0, stream>>>(x, w1, w2, out);
}

// Round 4
// 287.416 us; speedup vs baseline: 1.1564x; 1.1564x over previous
//
#include <hip/hip_runtime.h>

#define Tdim 4096
#define Bdim 8
#define Cdim 64
#define Ldim 15
#define Idim 2048   // T / STRIDE
#define OUTW 4160   // C + C*C
#define G    2      // windows per block
#define RX   (2*G + 27)   // 31 staged x rows
#define RXC  (2*G + 13)   // 17 centered rows
#define NBLK (Idim / G)   // 1024 blocks per batch

// One block = G=2 consecutive windows of one batch. 256 threads.
// vs R0 (G=4): accumulator 64->32 VGPRs -> 6 blocks/CU (24 waves) instead of 4
// (16 waves); 2x blocks -> finer interleave of staging/compute/store phases
// across the CU. P3 keeps the shared-row structure (each LDS row read once,
// scatter-FMA into every window whose tap range covers it). Single-barrier
// reduce: every thread sums the 4 per-wave partials itself (broadcast reads).
__global__ __launch_bounds__(256, 6) void cbp_kernel(const float* __restrict__ x,
                                                     const float* __restrict__ w1,
                                                     const float* __restrict__ w2,
                                                     float* __restrict__ out) {
    __shared__ float xbuf[RX][64];
    __shared__ float xcs[RXC][64];
    __shared__ float mus[G][64];
    __shared__ float red[4][G];

    const int tid = threadIdx.x;
    const int blk = blockIdx.x;
    const int b  = blk >> 10;            // / NBLK
    const int i0 = (blk & (NBLK - 1)) << 1;   // first window index (G=2)
    const int s0 = i0 << 1;                    // STRIDE = 2

    // ---- P1: stage 31 rows, float4, zero-padded ----
    const float* xb = x + (size_t)b * (Tdim * Cdim);
    for (int v = tid; v < RX * 16; v += 256) {
        const int r  = v >> 4;
        const int c4 = (v & 15) << 2;
        const int t  = s0 - 14 + r;
        float4 val = make_float4(0.f, 0.f, 0.f, 0.f);
        if (t >= 0 && t < Tdim) val = *(const float4*)(xb + (size_t)t * Cdim + c4);
        *(float4*)(&xbuf[r][c4]) = val;
    }
    __syncthreads();

    // ---- P2: 17 unique xc rows (272 float4 tasks); mu kept at j=7,9 ----
    for (int v = tid; v < RXC * 16; v += 256) {
        const int j  = v >> 4;
        const int c4 = (v & 15) << 2;
        const int t  = s0 - 7 + j;
        float4 m = make_float4(0.f, 0.f, 0.f, 0.f);
#pragma unroll
        for (int k = 0; k < Ldim; ++k) {
            const float w = w1[k];               // uniform -> s_load, hoisted
            const float4 xv = *(const float4*)(&xbuf[j + k][c4]);
            m.x = fmaf(w, xv.x, m.x);
            m.y = fmaf(w, xv.y, m.y);
            m.z = fmaf(w, xv.z, m.z);
            m.w = fmaf(w, xv.w, m.w);
        }
        const float4 xv = *(const float4*)(&xbuf[j + 7][c4]);
        float4 xc = make_float4(0.f, 0.f, 0.f, 0.f);
        if (t >= 0 && t < Tdim)
            xc = make_float4(xv.x - m.x, xv.y - m.y, xv.z - m.z, xv.w - m.w);
        *(float4*)(&xcs[j][c4]) = xc;
        if (j == 7 || j == 9)
            *(float4*)(&mus[(j - 7) >> 1][c4]) = m;   // always in-range (s0+2g < T)
    }
    __syncthreads();

    // ---- P3: shared-row Gram accumulation (32 acc VGPRs) ----
    const int c0 = (tid >> 4) << 2;   // 0..60
    const int d0 = (tid & 15) << 2;   // 0..60
    float acc[G][4][4];
#pragma unroll
    for (int g = 0; g < G; ++g)
#pragma unroll
        for (int cc = 0; cc < 4; ++cc)
#pragma unroll
            for (int dd = 0; dd < 4; ++dd) acc[g][cc][dd] = 0.f;

#pragma unroll
    for (int r = 0; r < RXC; ++r) {
        const float4 xd = *(const float4*)(&xcs[r][d0]);   // ds_read_b128
        const float4 xc = *(const float4*)(&xcs[r][c0]);   // ds_read_b128 (bcast)
#pragma unroll
        for (int g = 0; g < G; ++g) {
            const int l = r - 2 * g;
            if (l >= 0 && l < Ldim) {                       // static after unroll
                const float w  = w2[l];                     // s_load, hoisted
                const float a0 = w * xc.x, a1 = w * xc.y, a2 = w * xc.z, a3 = w * xc.w;
                acc[g][0][0] = fmaf(a0, xd.x, acc[g][0][0]);
                acc[g][0][1] = fmaf(a0, xd.y, acc[g][0][1]);
                acc[g][0][2] = fmaf(a0, xd.z, acc[g][0][2]);
                acc[g][0][3] = fmaf(a0, xd.w, acc[g][0][3]);
                acc[g][1][0] = fmaf(a1, xd.x, acc[g][1][0]);
                acc[g][1][1] = fmaf(a1, xd.y, acc[g][1][1]);
                acc[g][1][2] = fmaf(a1, xd.z, acc[g][1][2]);
                acc[g][1][3] = fmaf(a1, xd.w, acc[g][1][3]);
                acc[g][2][0] = fmaf(a2, xd.x, acc[g][2][0]);
                acc[g][2][1] = fmaf(a2, xd.y, acc[g][2][1]);
                acc[g][2][2] = fmaf(a2, xd.z, acc[g][2][2]);
                acc[g][2][3] = fmaf(a2, xd.w, acc[g][2][3]);
                acc[g][3][0] = fmaf(a3, xd.x, acc[g][3][0]);
                acc[g][3][1] = fmaf(a3, xd.y, acc[g][3][1]);
                acc[g][3][2] = fmaf(a3, xd.z, acc[g][3][2]);
                acc[g][3][3] = fmaf(a3, xd.w, acc[g][3][3]);
            }
        }
    }

    // ---- P4: per-window sum of squares, SINGLE barrier ----
    float local[G];
#pragma unroll
    for (int g = 0; g < G; ++g) {
        float s = 0.f;
#pragma unroll
        for (int cc = 0; cc < 4; ++cc)
#pragma unroll
            for (int dd = 0; dd < 4; ++dd) s = fmaf(acc[g][cc][dd], acc[g][cc][dd], s);
        local[g] = s;
    }
    if (tid < Cdim) {
#pragma unroll
        for (int g = 0; g < G; ++g) local[g] = fmaf(mus[g][tid], mus[g][tid], local[g]);
    }
#pragma unroll
    for (int off = 32; off; off >>= 1)
#pragma unroll
        for (int g = 0; g < G; ++g) local[g] += __shfl_down(local[g], off, 64);
    if ((tid & 63) == 0) {
        const int w = tid >> 6;
#pragma unroll
        for (int g = 0; g < G; ++g) red[w][g] = local[g];
    }
    __syncthreads();

    float scale[G];
#pragma unroll
    for (int g = 0; g < G; ++g) {
        const float ss = red[0][g] + red[1][g] + red[2][g] + red[3][g];  // broadcast
        scale[g] = rsqrtf(fmaxf(ss, 1e-12f));
    }

    // ---- Epilogue: coalesced plain stores ----
#pragma unroll
    for (int g = 0; g < G; ++g) {
        const float sc = scale[g];
        float* orow = out + (size_t)(b * Idim + i0 + g) * OUTW;
        if (tid < 16) {
            float4 m4 = *(const float4*)(&mus[g][tid << 2]);
            m4.x *= sc; m4.y *= sc; m4.z *= sc; m4.w *= sc;
            *(float4*)(orow + (tid << 2)) = m4;
        }
        float* osig = orow + Cdim;
#pragma unroll
        for (int cc = 0; cc < 4; ++cc) {
            const float4 v = make_float4(acc[g][cc][0] * sc, acc[g][cc][1] * sc,
                                         acc[g][cc][2] * sc, acc[g][cc][3] * sc);
            *(float4*)(osig + (c0 + cc) * Cdim + d0) = v;
        }
    }
}

extern "C" void kernel_launch(void* const* d_in, const int* in_sizes, int n_in,
                              void* d_out, int out_size, void* d_ws, size_t ws_size,
                              hipStream_t stream) {
    const float* x  = (const float*)d_in[0];
    const float* w1 = (const float*)d_in[1];
    const float* w2 = (const float*)d_in[2];
    float* out = (float*)d_out;
    cbp_kernel<<<dim3(Bdim * NBLK), dim3(256), 0, stream>>>(x, w1, w2, out);
}